// Round 2
// baseline (990.669 us; speedup 1.0000x reference)
//
#include <hip/hip_runtime.h>
#include <hip/hip_bf16.h>

typedef unsigned short u16;
typedef unsigned int u32;
typedef __bf16 v8bf __attribute__((ext_vector_type(8)));
typedef float v4f __attribute__((ext_vector_type(4)));

#define B_ROWS 1024
#define D_DIM  512
#define C_CLS  100000
#define SCALE_F 30.0f
#define MARGIN_F 0.4f
#define NY 782   // column chunks of 128; with -1 shift, chunk y covers cols [128y-1, 128y+126]

// pack two fp32 -> two bf16 (RNE)
__device__ __forceinline__ u32 rne2(float a, float b) {
    u32 ua = __float_as_uint(a), ub = __float_as_uint(b);
    ua = ua + 0x7FFFu + ((ua >> 16) & 1u);
    ub = ub + 0x7FFFu + ((ub >> 16) & 1u);
    return (ua >> 16) | (ub & 0xFFFF0000u);
}

// ---------------- prep x: row-normalize, convert to bf16, zero SUM ----------------
__global__ __launch_bounds__(64) void prep_x(const float* __restrict__ x,
                                             u16* __restrict__ XB,
                                             float* __restrict__ SUM) {
    const int row = blockIdx.x;
    const int lane = threadIdx.x;
    const float4* xr = (const float4*)(x + (size_t)row * D_DIM);
    float4 a = xr[lane];
    float4 b = xr[lane + 64];
    float s = a.x*a.x + a.y*a.y + a.z*a.z + a.w*a.w
            + b.x*b.x + b.y*b.y + b.z*b.z + b.w*b.w;
    #pragma unroll
    for (int m = 32; m > 0; m >>= 1) s += __shfl_xor(s, m, 64);
    const float inv = 1.0f / fmaxf(sqrtf(s), 1e-12f);
    uint2 pa, pb;
    pa.x = rne2(a.x*inv, a.y*inv); pa.y = rne2(a.z*inv, a.w*inv);
    pb.x = rne2(b.x*inv, b.y*inv); pb.y = rne2(b.z*inv, b.w*inv);
    *(uint2*)(XB + (size_t)row * D_DIM + lane*4)       = pa;
    *(uint2*)(XB + (size_t)row * D_DIM + 256 + lane*4) = pb;
    if (lane == 0) SUM[row] = 0.0f;  // zero for atomic accumulation (reduce_k / fallback)
}

// ---------------- prep w ----------------
template<bool WB_MODE>
__global__ __launch_bounds__(256) void prep_w(const float* __restrict__ w,
                                              u16* __restrict__ WB,
                                              float* __restrict__ invnw) {
    const int row = blockIdx.x * 4 + (threadIdx.x >> 6);
    const int lane = threadIdx.x & 63;
    const float4* wr = (const float4*)(w + (size_t)row * D_DIM);
    float4 a = wr[lane];
    float4 b = wr[lane + 64];
    float s = a.x*a.x + a.y*a.y + a.z*a.z + a.w*a.w
            + b.x*b.x + b.y*b.y + b.z*b.z + b.w*b.w;
    #pragma unroll
    for (int m = 32; m > 0; m >>= 1) s += __shfl_xor(s, m, 64);
    const float inv = 1.0f / fmaxf(sqrtf(s), 1e-12f);
    if (WB_MODE) {
        uint2 pa, pb;
        pa.x = rne2(a.x*inv, a.y*inv); pa.y = rne2(a.z*inv, a.w*inv);
        pb.x = rne2(b.x*inv, b.y*inv); pb.y = rne2(b.z*inv, b.w*inv);
        *(uint2*)(WB + (size_t)row * D_DIM + lane*4)       = pa;
        *(uint2*)(WB + (size_t)row * D_DIM + 256 + lane*4) = pb;
    } else {
        if (lane == 0) invnw[row] = inv;
    }
}

// ---------------- GEMM: cosine = XBn @ WBn^T, fused exp-sum epilogue ----------------
// tile 256(M) x 128(N), BK=64, 512 threads = 8 waves (4 along M x 2 along N).
// N-tiles shifted LEFT by one column (n0 = y*128 - 1): flat output (cosine at out+1)
// gets 16B-aligned stores; every 64B line written fully by one wave instruction.
// Round 2 experiment: PLAIN stores (nt removed) — testing whether the nt hint was
// causing sub-line HBM write bursts (WRITE_SIZE stuck at ~2.5x ideal with nt).
template<bool USE_WB>
__global__ __launch_bounds__(512, 4) void gemm_k(
        const u16* __restrict__ XB, const u16* __restrict__ WB,
        const float* __restrict__ W, const float* __restrict__ invnw,
        float* __restrict__ out, float* __restrict__ SUM,
        float* __restrict__ PS) {
    __shared__ __align__(16) char smem[55296];
    u16 (*sA)[72] = (u16(*)[72])smem;             // 256*72*2 = 36864
    u16 (*sB)[72] = (u16(*)[72])(smem + 36864);   // 128*72*2 = 18432
    float* sC = (float*)smem;                     // epilogue: 64*132*4 = 33792

    const int tid = threadIdx.x;
    const int m0 = blockIdx.x * 256;
    const int n0 = (int)blockIdx.y * 128 - 1;     // shifted column base (>= -1)
    const int lane = tid & 63;
    const int wv = tid >> 6;
    const int wm = wv & 3;        // 0..3 along M
    const int wn = wv >> 2;       // 0..1 along N
    const int col = lane & 15;
    const int quad = lane >> 4;

    v4f acc[4][4];
    #pragma unroll
    for (int mi = 0; mi < 4; ++mi)
        #pragma unroll
        for (int ni = 0; ni < 4; ++ni)
            acc[mi][ni] = (v4f){0.f, 0.f, 0.f, 0.f};

    for (int kt = 0; kt < 8; ++kt) {
        const int k0 = kt * 64;
        uint4 av[4];
        #pragma unroll
        for (int i = 0; i < 4; ++i) {
            int ch = tid + 512*i; int r = ch >> 3, c = ch & 7;
            av[i] = *(const uint4*)(XB + (size_t)(m0 + r) * D_DIM + k0 + c*8);
        }
        uint4 bv[2];
        if (USE_WB) {
            #pragma unroll
            for (int i = 0; i < 2; ++i) {
                int ch = tid + 512*i; int r = ch >> 3, c = ch & 7;
                int gc = n0 + r;                       // can be -1 or >= C
                bv[i] = ((unsigned)gc < (unsigned)C_CLS)
                      ? *(const uint4*)(WB + (size_t)gc * D_DIM + k0 + c*8)
                      : make_uint4(0u, 0u, 0u, 0u);
            }
        } else {
            #pragma unroll
            for (int i = 0; i < 2; ++i) {
                int ch = tid + 512*i; int r = ch >> 3, c = ch & 7;
                int gc = n0 + r;
                float4 f0, f1; float inv;
                if ((unsigned)gc < (unsigned)C_CLS) {
                    const float* p = W + (size_t)gc * D_DIM + k0 + c*8;
                    f0 = *(const float4*)p;
                    f1 = *(const float4*)(p + 4);
                    inv = invnw[gc];
                } else {
                    f0 = make_float4(0.f,0.f,0.f,0.f);
                    f1 = make_float4(0.f,0.f,0.f,0.f);
                    inv = 0.f;
                }
                uint4 pk;
                pk.x = rne2(f0.x*inv, f0.y*inv); pk.y = rne2(f0.z*inv, f0.w*inv);
                pk.z = rne2(f1.x*inv, f1.y*inv); pk.w = rne2(f1.z*inv, f1.w*inv);
                bv[i] = pk;
            }
        }
        __syncthreads();
        #pragma unroll
        for (int i = 0; i < 4; ++i) {
            int ch = tid + 512*i; int r = ch >> 3, c = ch & 7;
            *(uint4*)&sA[r][c*8] = av[i];
        }
        #pragma unroll
        for (int i = 0; i < 2; ++i) {
            int ch = tid + 512*i; int r = ch >> 3, c = ch & 7;
            *(uint4*)&sB[r][c*8] = bv[i];
        }
        __syncthreads();

        #pragma unroll
        for (int kk = 0; kk < 64; kk += 32) {
            v8bf af[4], bfv[4];
            #pragma unroll
            for (int mi = 0; mi < 4; ++mi)
                af[mi] = *(const v8bf*)&sA[wm*64 + mi*16 + col][kk + quad*8];
            #pragma unroll
            for (int ni = 0; ni < 4; ++ni)
                bfv[ni] = *(const v8bf*)&sB[wn*64 + ni*16 + col][kk + quad*8];
            #pragma unroll
            for (int mi = 0; mi < 4; ++mi)
                #pragma unroll
                for (int ni = 0; ni < 4; ++ni)
                    acc[mi][ni] = __builtin_amdgcn_mfma_f32_16x16x32_bf16(
                        af[mi], bfv[ni], acc[mi][ni], 0, 0, 0);
        }
    }

    // ---- epilogue: LDS bounce -> aligned full-line stores + per-row exp-sum ----
    const float e2s = 43.2808512266689f;   // 30 * log2(e)
    __syncthreads();   // all MFMA LDS reads done before overwriting smem
    #pragma unroll
    for (int mi = 0; mi < 4; ++mi) {
        // deposit this mi-chunk (64 rows x 128 cols) into LDS, stride 132 (2-way conflicts only)
        #pragma unroll
        for (int ni = 0; ni < 4; ++ni)
            #pragma unroll
            for (int r = 0; r < 4; ++r)
                sC[(wm*16 + quad*4 + r)*132 + wn*64 + ni*16 + col] = acc[mi][ni][r];
        __syncthreads();
        #pragma unroll
        for (int j = 0; j < 4; ++j) {
            const int li = tid + 512*j;
            const int lr = li >> 5;        // 0..63: local row
            const int sl = li & 31;        // 32 lanes cover a 128-col row
            v4f v = *(const v4f*)&sC[lr*132 + sl*4];
            const int gm = m0 + (lr >> 4)*64 + mi*16 + (lr & 15);
            const int gc = n0 + sl*4;      // first column of this 4-vector (>= -1)
            // column c lives at out + gm*C + (c+1); p[0] <-> column gc.
            // byte offset = gm*400000 + y*512 + sl*16 -> 16B aligned, 512B-contiguous
            // per 32-lane half-wave: full 64B/128B lines, single writer.
            float* p = out + (size_t)gm * C_CLS + (unsigned)(n0 + 1 + sl*4);
            float rs = 0.f;
            if ((unsigned)gc <= (unsigned)(C_CLS - 4)) {     // interior: full aligned vec
                *(v4f*)p = v;                                // plain cached store (nt removed)
                rs = exp2f(v[0]*e2s) + exp2f(v[1]*e2s)
                   + exp2f(v[2]*e2s) + exp2f(v[3]*e2s);
            } else {                                         // edges: y==0/sl==0 and top chunk
                #pragma unroll
                for (int e = 0; e < 4; ++e) {
                    const int c = gc + e;
                    if ((unsigned)c < (unsigned)C_CLS) {     // skips c==-1 (loss slot) and c>=C
                        p[e] = v[e];
                        rs += exp2f(v[e]*e2s);
                    }
                }
            }
            rs += __shfl_xor(rs, 1);
            rs += __shfl_xor(rs, 2);
            rs += __shfl_xor(rs, 4);
            rs += __shfl_xor(rs, 8);
            rs += __shfl_xor(rs, 16);
            if (sl == 0) {
                if (PS) PS[(size_t)blockIdx.y * B_ROWS + gm] = rs;  // coalesced, no atomics
                else    atomicAdd(&SUM[gm], rs);                    // fallback (tight ws)
            }
        }
        __syncthreads();
    }
}

// ---------------- reduce partial sums: SUM[r] += sum_y PS[y][r] ----------------
// Parallel over y-chunks: grid (4 row-groups x 8 y-chunks) x 256 thr, 4-way ILP.
// Old version (16 blocks, 782 serial dependent loads) was latency-bound.
__global__ __launch_bounds__(256) void reduce_k(const float* __restrict__ PS,
                                                float* __restrict__ SUM) {
    const int r  = blockIdx.x * 256 + threadIdx.x;   // 0..1023
    const int y0 = blockIdx.y * 98;
    const int y1 = (y0 + 98 < NY) ? y0 + 98 : NY;
    float s0 = 0.f, s1 = 0.f, s2 = 0.f, s3 = 0.f;
    int y = y0;
    for (; y + 4 <= y1; y += 4) {
        s0 += PS[(size_t)(y+0) * B_ROWS + r];        // coalesced across lanes
        s1 += PS[(size_t)(y+1) * B_ROWS + r];
        s2 += PS[(size_t)(y+2) * B_ROWS + r];
        s3 += PS[(size_t)(y+3) * B_ROWS + r];
    }
    for (; y < y1; ++y) s0 += PS[(size_t)y * B_ROWS + r];
    atomicAdd(&SUM[r], (s0 + s1) + (s2 + s3));       // SUM pre-zeroed by prep_x
}

// ---------------- final loss: one thread per batch row ----------------
__global__ __launch_bounds__(1024) void loss_k(const float* __restrict__ out,
                                               const int* __restrict__ label,
                                               const float* __restrict__ SUM,
                                               float* __restrict__ out0) {
    __shared__ float red[1024];
    const int t = threadIdx.x;
    const float tgt = out[1 + (size_t)t * C_CLS + label[t]];
    const float num = SCALE_F * (tgt - MARGIN_F);
    const float ex_t = expf(SCALE_F * tgt);
    const float denom = expf(num) + (SUM[t] - ex_t);
    red[t] = num - logf(denom);
    __syncthreads();
    for (int s = 512; s > 0; s >>= 1) {
        if (t < s) red[t] += red[t + s];
        __syncthreads();
    }
    if (t == 0) out0[0] = -red[0] / (float)B_ROWS;
}

extern "C" void kernel_launch(void* const* d_in, const int* in_sizes, int n_in,
                              void* d_out, int out_size, void* d_ws, size_t ws_size,
                              hipStream_t stream) {
    const float* x     = (const float*)d_in[0];
    const int*   label = (const int*)d_in[1];
    const float* w     = (const float*)d_in[2];
    float* out = (float*)d_out;
    char*  ws  = (char*)d_ws;

    float* SUM   = (float*)ws;                       // 4 KB
    float* invnw = (float*)(ws + 4096);              // 400 KB
    u16*   XB    = (u16*)(ws + 512*1024);            // 1 MB
    u16*   WB    = (u16*)(ws + 2*1024*1024);         // 102.4 MB (optional)
    const size_t wb_need = (size_t)2*1024*1024 + (size_t)C_CLS * D_DIM * 2;
    const bool use_wb = ws_size >= wb_need;

    // partial-sum buffer after WB (or at 2MB if WB mode is off); atomic fallback if absent
    const size_t ps_off  = use_wb ? wb_need : (size_t)2*1024*1024;
    const size_t ps_need = ps_off + (size_t)NY * B_ROWS * sizeof(float);  // +3.2 MB
    float* PS = (ws_size >= ps_need) ? (float*)(ws + ps_off) : nullptr;

    prep_x<<<dim3(B_ROWS), dim3(64), 0, stream>>>(x, XB, SUM);

    const dim3 ggrid(B_ROWS / 256, NY);  // (4, 782), M fastest
    if (use_wb) {
        prep_w<true><<<dim3(C_CLS / 4), dim3(256), 0, stream>>>(w, WB, invnw);
        gemm_k<true><<<ggrid, dim3(512), 0, stream>>>(XB, WB, nullptr, nullptr, out, SUM, PS);
    } else {
        prep_w<false><<<dim3(C_CLS / 4), dim3(256), 0, stream>>>(w, WB, invnw);
        gemm_k<false><<<ggrid, dim3(512), 0, stream>>>(XB, nullptr, w, invnw, out, SUM, PS);
    }
    if (PS) reduce_k<<<dim3(4, 8), dim3(256), 0, stream>>>(PS, SUM);
    loss_k<<<dim3(1), dim3(1024), 0, stream>>>(out, label, SUM, out);
}

// Round 3
// 744.116 us; speedup vs baseline: 1.3313x; 1.3313x over previous
//
#include <hip/hip_runtime.h>
#include <hip/hip_bf16.h>

typedef unsigned short u16;
typedef unsigned int u32;
typedef __bf16 v8bf __attribute__((ext_vector_type(8)));
typedef float v4f __attribute__((ext_vector_type(4)));

#define B_ROWS 1024
#define D_DIM  512
#define C_CLS  100000
#define SCALE_F 30.0f
#define MARGIN_F 0.4f
#define NY 782      // column chunks of 128; with -1 shift, chunk y covers cols [128y-1, 128y+126]
#define NWG 3128    // 4 M-tiles x 782 y-chunks; 3128 = 8 XCDs x 391

// pack two fp32 -> two bf16 (RNE)
__device__ __forceinline__ u32 rne2(float a, float b) {
    u32 ua = __float_as_uint(a), ub = __float_as_uint(b);
    ua = ua + 0x7FFFu + ((ua >> 16) & 1u);
    ub = ub + 0x7FFFu + ((ub >> 16) & 1u);
    return (ua >> 16) | (ub & 0xFFFF0000u);
}

// ---------------- prep x: row-normalize, convert to bf16, zero SUM ----------------
__global__ __launch_bounds__(64) void prep_x(const float* __restrict__ x,
                                             u16* __restrict__ XB,
                                             float* __restrict__ SUM) {
    const int row = blockIdx.x;
    const int lane = threadIdx.x;
    const float4* xr = (const float4*)(x + (size_t)row * D_DIM);
    float4 a = xr[lane];
    float4 b = xr[lane + 64];
    float s = a.x*a.x + a.y*a.y + a.z*a.z + a.w*a.w
            + b.x*b.x + b.y*b.y + b.z*b.z + b.w*b.w;
    #pragma unroll
    for (int m = 32; m > 0; m >>= 1) s += __shfl_xor(s, m, 64);
    const float inv = 1.0f / fmaxf(sqrtf(s), 1e-12f);
    uint2 pa, pb;
    pa.x = rne2(a.x*inv, a.y*inv); pa.y = rne2(a.z*inv, a.w*inv);
    pb.x = rne2(b.x*inv, b.y*inv); pb.y = rne2(b.z*inv, b.w*inv);
    *(uint2*)(XB + (size_t)row * D_DIM + lane*4)       = pa;
    *(uint2*)(XB + (size_t)row * D_DIM + 256 + lane*4) = pb;
    if (lane == 0) SUM[row] = 0.0f;  // zero for atomic accumulation (reduce_k / fallback)
}

// ---------------- prep w ----------------
template<bool WB_MODE>
__global__ __launch_bounds__(256) void prep_w(const float* __restrict__ w,
                                              u16* __restrict__ WB,
                                              float* __restrict__ invnw) {
    const int row = blockIdx.x * 4 + (threadIdx.x >> 6);
    const int lane = threadIdx.x & 63;
    const float4* wr = (const float4*)(w + (size_t)row * D_DIM);
    float4 a = wr[lane];
    float4 b = wr[lane + 64];
    float s = a.x*a.x + a.y*a.y + a.z*a.z + a.w*a.w
            + b.x*b.x + b.y*b.y + b.z*b.z + b.w*b.w;
    #pragma unroll
    for (int m = 32; m > 0; m >>= 1) s += __shfl_xor(s, m, 64);
    const float inv = 1.0f / fmaxf(sqrtf(s), 1e-12f);
    if (WB_MODE) {
        uint2 pa, pb;
        pa.x = rne2(a.x*inv, a.y*inv); pa.y = rne2(a.z*inv, a.w*inv);
        pb.x = rne2(b.x*inv, b.y*inv); pb.y = rne2(b.z*inv, b.w*inv);
        *(uint2*)(WB + (size_t)row * D_DIM + lane*4)       = pa;
        *(uint2*)(WB + (size_t)row * D_DIM + 256 + lane*4) = pb;
    } else {
        if (lane == 0) invnw[row] = inv;
    }
}

// ---------------- GEMM: cosine = XBn @ WBn^T, fused exp-sum epilogue ----------------
// tile 256(M) x 128(N), BK=32 (16 K-steps), 512 threads = 8 waves (4 M x 2 N).
// Round 3:
//  - BK 64->32, row stride 40 elems (80B, 16B-aligned): LDS 55.3KB -> 33.8KB
//    => 4 blocks/CU capable (was LDS-capped at 2). Bank pattern of stride-40
//    b128 reads is the same multiple-of-4-dword family as stride-72 (no regression).
//  - register-staged software pipeline: preload tile 0; issue tile t+1 loads after
//    the ds_writes of tile t so HBM/L2 latency hides under MFMA + barrier.
//  - nt stores restored (round-2 A/B: plain stores cost +67us, +fetch, +write).
//  - XCD-chunked swizzle: 4 same-y M-tiles run consecutively on ONE XCD => WB
//    slice fetched once, L2-hit x3 (FETCH was 2.7x WB size with round-robin).
template<bool USE_WB>
__global__ __launch_bounds__(512, 4) void gemm_k(
        const u16* __restrict__ XB, const u16* __restrict__ WB,
        const float* __restrict__ W, const float* __restrict__ invnw,
        float* __restrict__ out, float* __restrict__ SUM,
        float* __restrict__ PS) {
    __shared__ __align__(16) char smem[33792];
    u16 (*sA)[40] = (u16(*)[40])smem;             // 256*40*2 = 20480
    u16 (*sB)[40] = (u16(*)[40])(smem + 20480);   // 128*40*2 = 10240 (total 30720)
    float* sC = (float*)smem;                     // epilogue: 64*132*4 = 33792

    const int tid = threadIdx.x;
    // XCD-chunked bijective swizzle: hw block b -> original flat o = x + 4*y.
    // b%8 = XCD; each XCD gets a contiguous chunk of 391 original indices.
    const int b = blockIdx.x;
    const int o = (b & 7) * (NWG / 8) + (b >> 3);
    const int m0 = (o & 3) * 256;
    const int y  = o >> 2;
    const int n0 = y * 128 - 1;                   // shifted column base (>= -1)

    const int lane = tid & 63;
    const int wv = tid >> 6;
    const int wm = wv & 3;        // 0..3 along M
    const int wn = wv >> 2;       // 0..1 along N
    const int col = lane & 15;
    const int quad = lane >> 4;

    // A staging: 256 rows x 4 chunks(16B) = 1024 -> 2/thread
    const int ar0 = tid >> 2,          ac0 = (tid & 3) * 8;
    const int ar1 = (tid + 512) >> 2,  ac1 = ac0;     // same c pattern, rows 128..255
    // B staging: 128 rows x 4 chunks = 512 -> 1/thread
    const int br = tid >> 2,           bc = (tid & 3) * 8;
    const int bgc = n0 + br;                          // can be -1 or >= C

    v4f acc[4][4];
    #pragma unroll
    for (int mi = 0; mi < 4; ++mi)
        #pragma unroll
        for (int ni = 0; ni < 4; ++ni)
            acc[mi][ni] = (v4f){0.f, 0.f, 0.f, 0.f};

    // ---- preload K-step 0 into registers ----
    uint4 av0, av1, bv;
    {
        av0 = *(const uint4*)(XB + (size_t)(m0 + ar0) * D_DIM + ac0);
        av1 = *(const uint4*)(XB + (size_t)(m0 + ar1) * D_DIM + ac1);
        if (USE_WB) {
            bv = ((unsigned)bgc < (unsigned)C_CLS)
               ? *(const uint4*)(WB + (size_t)bgc * D_DIM + bc)
               : make_uint4(0u, 0u, 0u, 0u);
        } else {
            float4 f0, f1; float inv;
            if ((unsigned)bgc < (unsigned)C_CLS) {
                const float* p = W + (size_t)bgc * D_DIM + bc;
                f0 = *(const float4*)p; f1 = *(const float4*)(p + 4);
                inv = invnw[bgc];
            } else {
                f0 = make_float4(0.f,0.f,0.f,0.f);
                f1 = make_float4(0.f,0.f,0.f,0.f);
                inv = 0.f;
            }
            bv.x = rne2(f0.x*inv, f0.y*inv); bv.y = rne2(f0.z*inv, f0.w*inv);
            bv.z = rne2(f1.x*inv, f1.y*inv); bv.w = rne2(f1.z*inv, f1.w*inv);
        }
    }

    for (int kt = 0; kt < 16; ++kt) {
        __syncthreads();                       // prior MFMA LDS reads done
        *(uint4*)&sA[ar0][ac0] = av0;          // (compiler inserts vmcnt wait here)
        *(uint4*)&sA[ar1][ac1] = av1;
        *(uint4*)&sB[br][bc]   = bv;
        __syncthreads();

        // issue next K-step's global loads now -> latency hides under MFMA+barrier.
        // last iter wraps to k=0 (valid addresses, result unused).
        const int kn = ((kt + 1) & 15) * 32;
        av0 = *(const uint4*)(XB + (size_t)(m0 + ar0) * D_DIM + kn + ac0);
        av1 = *(const uint4*)(XB + (size_t)(m0 + ar1) * D_DIM + kn + ac1);
        if (USE_WB) {
            bv = ((unsigned)bgc < (unsigned)C_CLS)
               ? *(const uint4*)(WB + (size_t)bgc * D_DIM + kn + bc)
               : make_uint4(0u, 0u, 0u, 0u);
        } else {
            float4 f0, f1; float inv;
            if ((unsigned)bgc < (unsigned)C_CLS) {
                const float* p = W + (size_t)bgc * D_DIM + kn + bc;
                f0 = *(const float4*)p; f1 = *(const float4*)(p + 4);
                inv = invnw[bgc];
            } else {
                f0 = make_float4(0.f,0.f,0.f,0.f);
                f1 = make_float4(0.f,0.f,0.f,0.f);
                inv = 0.f;
            }
            bv.x = rne2(f0.x*inv, f0.y*inv); bv.y = rne2(f0.z*inv, f0.w*inv);
            bv.z = rne2(f1.x*inv, f1.y*inv); bv.w = rne2(f1.z*inv, f1.w*inv);
        }

        v8bf af[4], bfv[4];
        #pragma unroll
        for (int mi = 0; mi < 4; ++mi)
            af[mi] = *(const v8bf*)&sA[wm*64 + mi*16 + col][quad*8];
        #pragma unroll
        for (int ni = 0; ni < 4; ++ni)
            bfv[ni] = *(const v8bf*)&sB[wn*64 + ni*16 + col][quad*8];
        #pragma unroll
        for (int mi = 0; mi < 4; ++mi)
            #pragma unroll
            for (int ni = 0; ni < 4; ++ni)
                acc[mi][ni] = __builtin_amdgcn_mfma_f32_16x16x32_bf16(
                    af[mi], bfv[ni], acc[mi][ni], 0, 0, 0);
    }

    // ---- epilogue: LDS bounce -> aligned nt full-line stores + per-row exp-sum ----
    const float e2s = 43.2808512266689f;   // 30 * log2(e)
    __syncthreads();   // all MFMA LDS reads done before overwriting smem
    #pragma unroll
    for (int mi = 0; mi < 4; ++mi) {
        // deposit this mi-chunk (64 rows x 128 cols) into LDS, stride 132 (2-way conflicts only)
        #pragma unroll
        for (int ni = 0; ni < 4; ++ni)
            #pragma unroll
            for (int r = 0; r < 4; ++r)
                sC[(wm*16 + quad*4 + r)*132 + wn*64 + ni*16 + col] = acc[mi][ni][r];
        __syncthreads();
        #pragma unroll
        for (int j = 0; j < 4; ++j) {
            const int li = tid + 512*j;
            const int lr = li >> 5;        // 0..63: local row
            const int sl = li & 31;        // 32 lanes cover a 128-col row
            v4f v = *(const v4f*)&sC[lr*132 + sl*4];
            const int gm = m0 + (lr >> 4)*64 + mi*16 + (lr & 15);
            const int gc = n0 + sl*4;      // first column of this 4-vector (>= -1)
            // column c lives at out + gm*C + (c+1); p[0] <-> column gc.
            // byte offset = gm*400000 + y*512 + sl*16 -> 16B aligned, full-line writes.
            float* p = out + (size_t)gm * C_CLS + (unsigned)(n0 + 1 + sl*4);
            float rs = 0.f;
            if ((unsigned)gc <= (unsigned)(C_CLS - 4)) {     // interior: full aligned vec
                __builtin_nontemporal_store(v, (v4f*)p);     // streaming past L2 (round-2 A/B)
                rs = exp2f(v[0]*e2s) + exp2f(v[1]*e2s)
                   + exp2f(v[2]*e2s) + exp2f(v[3]*e2s);
            } else {                                         // edges: y==0/sl==0 and top chunk
                #pragma unroll
                for (int e = 0; e < 4; ++e) {
                    const int c = gc + e;
                    if ((unsigned)c < (unsigned)C_CLS) {     // skips c==-1 (loss slot) and c>=C
                        p[e] = v[e];
                        rs += exp2f(v[e]*e2s);
                    }
                }
            }
            rs += __shfl_xor(rs, 1);
            rs += __shfl_xor(rs, 2);
            rs += __shfl_xor(rs, 4);
            rs += __shfl_xor(rs, 8);
            rs += __shfl_xor(rs, 16);
            if (sl == 0) {
                if (PS) PS[(size_t)y * B_ROWS + gm] = rs;    // coalesced, no atomics
                else    atomicAdd(&SUM[gm], rs);             // fallback (tight ws)
            }
        }
        __syncthreads();
    }
}

// ---------------- reduce partial sums: SUM[r] += sum_y PS[y][r] ----------------
// Parallel over y-chunks: grid (4 row-groups x 8 y-chunks) x 256 thr, 4-way ILP.
__global__ __launch_bounds__(256) void reduce_k(const float* __restrict__ PS,
                                                float* __restrict__ SUM) {
    const int r  = blockIdx.x * 256 + threadIdx.x;   // 0..1023
    const int y0 = blockIdx.y * 98;
    const int y1 = (y0 + 98 < NY) ? y0 + 98 : NY;
    float s0 = 0.f, s1 = 0.f, s2 = 0.f, s3 = 0.f;
    int y = y0;
    for (; y + 4 <= y1; y += 4) {
        s0 += PS[(size_t)(y+0) * B_ROWS + r];        // coalesced across lanes
        s1 += PS[(size_t)(y+1) * B_ROWS + r];
        s2 += PS[(size_t)(y+2) * B_ROWS + r];
        s3 += PS[(size_t)(y+3) * B_ROWS + r];
    }
    for (; y < y1; ++y) s0 += PS[(size_t)y * B_ROWS + r];
    atomicAdd(&SUM[r], (s0 + s1) + (s2 + s3));       // SUM pre-zeroed by prep_x
}

// ---------------- final loss: one thread per batch row ----------------
__global__ __launch_bounds__(1024) void loss_k(const float* __restrict__ out,
                                               const int* __restrict__ label,
                                               const float* __restrict__ SUM,
                                               float* __restrict__ out0) {
    __shared__ float red[1024];
    const int t = threadIdx.x;
    const float tgt = out[1 + (size_t)t * C_CLS + label[t]];
    const float num = SCALE_F * (tgt - MARGIN_F);
    const float ex_t = expf(SCALE_F * tgt);
    const float denom = expf(num) + (SUM[t] - ex_t);
    red[t] = num - logf(denom);
    __syncthreads();
    for (int s = 512; s > 0; s >>= 1) {
        if (t < s) red[t] += red[t + s];
        __syncthreads();
    }
    if (t == 0) out0[0] = -red[0] / (float)B_ROWS;
}

extern "C" void kernel_launch(void* const* d_in, const int* in_sizes, int n_in,
                              void* d_out, int out_size, void* d_ws, size_t ws_size,
                              hipStream_t stream) {
    const float* x     = (const float*)d_in[0];
    const int*   label = (const int*)d_in[1];
    const float* w     = (const float*)d_in[2];
    float* out = (float*)d_out;
    char*  ws  = (char*)d_ws;

    float* SUM   = (float*)ws;                       // 4 KB
    float* invnw = (float*)(ws + 4096);              // 400 KB
    u16*   XB    = (u16*)(ws + 512*1024);            // 1 MB
    u16*   WB    = (u16*)(ws + 2*1024*1024);         // 102.4 MB (optional)
    const size_t wb_need = (size_t)2*1024*1024 + (size_t)C_CLS * D_DIM * 2;
    const bool use_wb = ws_size >= wb_need;

    // partial-sum buffer after WB (or at 2MB if WB mode is off); atomic fallback if absent
    const size_t ps_off  = use_wb ? wb_need : (size_t)2*1024*1024;
    const size_t ps_need = ps_off + (size_t)NY * B_ROWS * sizeof(float);  // +3.2 MB
    float* PS = (ws_size >= ps_need) ? (float*)(ws + ps_off) : nullptr;

    prep_x<<<dim3(B_ROWS), dim3(64), 0, stream>>>(x, XB, SUM);

    if (use_wb) {
        prep_w<true><<<dim3(C_CLS / 4), dim3(256), 0, stream>>>(w, WB, invnw);
        gemm_k<true><<<dim3(NWG), dim3(512), 0, stream>>>(XB, WB, nullptr, nullptr, out, SUM, PS);
    } else {
        prep_w<false><<<dim3(C_CLS / 4), dim3(256), 0, stream>>>(w, WB, invnw);
        gemm_k<false><<<dim3(NWG), dim3(512), 0, stream>>>(XB, nullptr, w, invnw, out, SUM, PS);
    }
    if (PS) reduce_k<<<dim3(4, 8), dim3(256), 0, stream>>>(PS, SUM);
    loss_k<<<dim3(1), dim3(1024), 0, stream>>>(out, label, SUM, out);
}